// Round 1
// baseline (689.888 us; speedup 1.0000x reference)
//
#include <hip/hip_runtime.h>
#include <math.h>

#define NN 50000
#define EE 800000
#define RAWD 128
#define HIDD 256
#define OUTD 64
#define KK 4
#define PHID 16

// ---------------------------------------------------------------------------
// Tiled f32 GEMM: C[nrows, M] = act(A[nrows, KD] @ B' + bias)
//   TRB=false: B is [KD, M] row-major  (B'[k][m] = B[k*M+m])
//   TRB=true : B is [M, KD] row-major  (B'[k][m] = B[m*KD+k])
// 64x64 tile, BK=32, 256 threads, 4x4 micro-tile.
// ---------------------------------------------------------------------------
template <int KD, bool TRB, bool RELU>
__global__ __launch_bounds__(256) void gemm_k(const float* __restrict__ A,
                                              const float* __restrict__ B,
                                              const float* __restrict__ bias_vec,
                                              float* __restrict__ C,
                                              int nrows, int M) {
    const int BM = 64, BN = 64, BK = 32;
    __shared__ __align__(16) float As[BK][BM + 4];
    __shared__ __align__(16) float Bs[BK][BN + 4];
    const int row0 = blockIdx.x * BM;
    const int col0 = blockIdx.y * BN;
    const int tid = threadIdx.x;
    const int tr = tid >> 4;   // 0..15
    const int tc = tid & 15;   // 0..15
    float acc[4][4] = {};

    for (int k0 = 0; k0 < KD; k0 += BK) {
        // A tile: 64 rows x 32 k  (coalesced along k)
        #pragma unroll
        for (int i = tid; i < BM * BK; i += 256) {
            int m = i >> 5, kk = i & 31;
            int gr = row0 + m;
            As[kk][m] = (gr < nrows) ? A[(size_t)gr * KD + (k0 + kk)] : 0.f;
        }
        if (!TRB) {
            #pragma unroll
            for (int i = tid; i < BK * BN; i += 256) {
                int kk = i >> 6, n = i & 63;
                int gc = col0 + n;
                Bs[kk][n] = (gc < M) ? B[(size_t)(k0 + kk) * M + gc] : 0.f;
            }
        } else {
            #pragma unroll
            for (int i = tid; i < BK * BN; i += 256) {
                int n = i >> 5, kk = i & 31;
                int gc = col0 + n;
                Bs[kk][n] = (gc < M) ? B[(size_t)gc * KD + (k0 + kk)] : 0.f;
            }
        }
        __syncthreads();
        #pragma unroll
        for (int kk = 0; kk < BK; ++kk) {
            float4 av = *(const float4*)&As[kk][tr * 4];
            float4 bv = *(const float4*)&Bs[kk][tc * 4];
            float a_[4] = {av.x, av.y, av.z, av.w};
            float b_[4] = {bv.x, bv.y, bv.z, bv.w};
            #pragma unroll
            for (int i = 0; i < 4; ++i)
                #pragma unroll
                for (int j = 0; j < 4; ++j)
                    acc[i][j] += a_[i] * b_[j];
        }
        __syncthreads();
    }

    #pragma unroll
    for (int i = 0; i < 4; ++i) {
        int gr = row0 + tr * 4 + i;
        if (gr >= nrows) continue;
        #pragma unroll
        for (int j = 0; j < 4; ++j) {
            int gc = col0 + tc * 4 + j;
            if (gc >= M) continue;
            float v = acc[i][j];
            if (bias_vec) v += bias_vec[gc];
            if (RELU) v = fmaxf(v, 0.f);
            C[(size_t)gr * M + gc] = v;
        }
    }
}

// ---------------------------------------------------------------------------
// tilde_norm + l_sep (tiny), writes tnorm[64] to ws and l_sep to out scalar
// ---------------------------------------------------------------------------
__global__ void tnorm_lsep_k(const float* __restrict__ tilde_phi,
                             float* __restrict__ tnorm,
                             float* __restrict__ lsep_out) {
    __shared__ float tn[KK][PHID];
    int t = threadIdx.x;
    if (t < KK * PHID) {
        float v = tilde_phi[t];
        float sq = v * v;
        #pragma unroll
        for (int s = 8; s; s >>= 1) sq += __shfl_xor(sq, s, 16);
        float tnv = v / sqrtf(sq);
        tn[t >> 4][t & 15] = tnv;
        tnorm[t] = tnv;
    }
    __syncthreads();
    if (t == 0) {
        float tot = 0.f;
        for (int i = 0; i < KK; ++i)
            for (int j = 0; j < KK; ++j) {
                float s2 = 0.f;
                for (int p = 0; p < PHID; ++p) {
                    float df = tn[i][p] - tn[j][p];
                    s2 += df * df;
                }
                tot += s2;
            }
        lsep_out[0] = tot / (float)KK;
    }
}

// ---------------------------------------------------------------------------
// degree count
// ---------------------------------------------------------------------------
__global__ void degree_k(const int* __restrict__ dst, int* __restrict__ deg) {
    int e = blockIdx.x * 256 + threadIdx.x;
    if (e < EE) atomicAdd(&deg[dst[e]], 1);
}

// ---------------------------------------------------------------------------
// single-block inclusive scan -> offs[N+1]; cursor[i] = offs[i]
// ---------------------------------------------------------------------------
__global__ __launch_bounds__(1024) void scan_k(const int* __restrict__ deg,
                                               int* __restrict__ offs,
                                               int* __restrict__ cursor, int n) {
    __shared__ int sd[1024];
    __shared__ int carry_s;
    int tid = threadIdx.x;
    if (tid == 0) { offs[0] = 0; carry_s = 0; }
    __syncthreads();
    for (int base = 0; base < n; base += 1024) {
        int i = base + tid;
        int v = (i < n) ? deg[i] : 0;
        sd[tid] = v;
        __syncthreads();
        for (int s = 1; s < 1024; s <<= 1) {
            int t = (tid >= s) ? sd[tid - s] : 0;
            __syncthreads();
            sd[tid] += t;
            __syncthreads();
        }
        int inc = sd[tid] + carry_s;
        if (i < n) { offs[i + 1] = inc; cursor[i] = inc - v; }
        __syncthreads();
        if (tid == 1023) carry_s = inc;
        __syncthreads();
    }
}

// ---------------------------------------------------------------------------
// edge pass: dist -> normalized -> 4 logits, scatter into CSR slot of dst
// ---------------------------------------------------------------------------
__global__ __launch_bounds__(256) void edge_k(const float* __restrict__ phi,
                                              const float* __restrict__ delta,
                                              const float* __restrict__ tnorm,
                                              const int* __restrict__ src,
                                              const int* __restrict__ dst,
                                              int* __restrict__ cursor,
                                              int* __restrict__ csr_src,
                                              float4* __restrict__ csr_a) {
    __shared__ float tn[KK * PHID];
    if (threadIdx.x < KK * PHID) tn[threadIdx.x] = tnorm[threadIdx.x];
    __syncthreads();
    int e = blockIdx.x * 256 + threadIdx.x;
    if (e >= EE) return;
    int s = src[e], d = dst[e];
    const float* ps = phi + (size_t)s * 15;
    const float* pd = phi + (size_t)d * 15;
    float dv[16];
    bool allz = true;
    float nrm2 = 0.f;
    #pragma unroll
    for (int p = 0; p < 15; ++p) {
        float x = ps[p] - pd[p];
        dv[p] = x;
        allz = allz && (x == 0.f);
        nrm2 += x * x;
    }
    dv[15] = allz ? 1.f : 0.f;
    nrm2 += dv[15];
    float inv = 1.f / fmaxf(sqrtf(nrm2), 1e-8f);
    const float* dl = delta + (size_t)d * 64;
    float res[4];
    #pragma unroll
    for (int k = 0; k < 4; ++k) {
        float sacc = 0.f;
        #pragma unroll
        for (int p = 0; p < 16; ++p)
            sacc += dv[p] * (tn[k * 16 + p] + dl[k * 16 + p]);
        res[k] = sacc * inv;
    }
    int pos = atomicAdd(&cursor[d], 1);
    csr_src[pos] = s;
    csr_a[pos] = make_float4(res[0], res[1], res[2], res[3]);
}

// ---------------------------------------------------------------------------
// per-dst: softmax denom + weighted aggregation of h[src] + row-normalize
// one wave (64 lanes) per node; lane = output channel
// ---------------------------------------------------------------------------
__global__ __launch_bounds__(256) void aggregate_k(const int* __restrict__ offs,
                                                   const int* __restrict__ csr_src,
                                                   const float4* __restrict__ csr_a,
                                                   const float* __restrict__ h,
                                                   const float* __restrict__ bias,
                                                   float* __restrict__ out) {
    int wave = threadIdx.x >> 6;
    int lane = threadIdx.x & 63;
    int n = blockIdx.x * 4 + wave;
    if (n >= NN) return;
    int beg = offs[n], end = offs[n + 1];

    // pass 1: softmax denominators (no max-sub needed: |a| <= ||delta_ik|| small)
    float d0 = 0.f, d1 = 0.f, d2 = 0.f, d3 = 0.f;
    for (int p = beg + lane; p < end; p += 64) {
        float4 av = csr_a[p];
        d0 += __expf(av.x); d1 += __expf(av.y);
        d2 += __expf(av.z); d3 += __expf(av.w);
    }
    #pragma unroll
    for (int s = 32; s; s >>= 1) {
        d0 += __shfl_xor(d0, s); d1 += __shfl_xor(d1, s);
        d2 += __shfl_xor(d2, s); d3 += __shfl_xor(d3, s);
    }
    float i0 = (d0 > 0.f) ? 1.f / d0 : 0.f;
    float i1 = (d1 > 0.f) ? 1.f / d1 : 0.f;
    float i2 = (d2 > 0.f) ? 1.f / d2 : 0.f;
    float i3 = (d3 > 0.f) ? 1.f / d3 : 0.f;

    // pass 2: aggregate
    float acc = 0.f;
    for (int p = beg; p < end; ++p) {
        float4 av = csr_a[p];
        int sn = csr_src[p];
        float w0 = __expf(av.x) * i0;
        float w1 = __expf(av.y) * i1;
        float w2 = __expf(av.z) * i2;
        float w3 = __expf(av.w) * i3;
        const float* hr = h + (size_t)sn * 256;
        acc += hr[lane] * w0 + hr[64 + lane] * w1 + hr[128 + lane] * w2 + hr[192 + lane] * w3;
    }
    acc += bias[lane];
    float nr = acc * acc;
    #pragma unroll
    for (int s = 32; s; s >>= 1) nr += __shfl_xor(nr, s);
    float invn = 1.f / fmaxf(sqrtf(nr), 1e-8f);
    out[(size_t)n * 64 + lane] = acc * invn;
}

// ---------------------------------------------------------------------------
// l_focus reduction
// ---------------------------------------------------------------------------
__global__ void lfocus_partial_k(const float* __restrict__ delta,
                                 float* __restrict__ part, int count) {
    __shared__ float sd[256];
    float s = 0.f;
    for (int i = blockIdx.x * 256 + threadIdx.x; i < count; i += gridDim.x * 256) {
        float v = delta[i];
        s += v * v;
    }
    sd[threadIdx.x] = s;
    __syncthreads();
    for (int st = 128; st; st >>= 1) {
        if (threadIdx.x < st) sd[threadIdx.x] += sd[threadIdx.x + st];
        __syncthreads();
    }
    if (threadIdx.x == 0) part[blockIdx.x] = sd[0];
}

__global__ void lfocus_final_k(const float* __restrict__ part, int nb,
                               float* __restrict__ outp) {
    __shared__ float sd[256];
    float s = 0.f;
    for (int i = threadIdx.x; i < nb; i += 256) s += part[i];
    sd[threadIdx.x] = s;
    __syncthreads();
    for (int st = 128; st; st >>= 1) {
        if (threadIdx.x < st) sd[threadIdx.x] += sd[threadIdx.x + st];
        __syncthreads();
    }
    if (threadIdx.x == 0) outp[0] = sd[0] / (float)((size_t)NN * KK);
}

// ---------------------------------------------------------------------------
extern "C" void kernel_launch(void* const* d_in, const int* in_sizes, int n_in,
                              void* d_out, int out_size, void* d_ws, size_t ws_size,
                              hipStream_t stream) {
    const float* h_l       = (const float*)d_in[0];
    const float* e_l       = (const float*)d_in[1];
    const int*   src       = (const int*)d_in[2];
    const int*   dst       = (const int*)d_in[3];
    const float* W_phi     = (const float*)d_in[4];
    const float* W1        = (const float*)d_in[5];
    const float* b1        = (const float*)d_in[6];
    const float* W2        = (const float*)d_in[7];
    const float* b2        = (const float*)d_in[8];
    const float* tilde_phi = (const float*)d_in[9];
    const float* W         = (const float*)d_in[10];
    const float* bias      = (const float*)d_in[11];
    float* out = (float*)d_out;

    char* ws = (char*)d_ws;
    size_t off = 0;
    auto alloc = [&](size_t bytes) -> char* {
        char* p = ws + off;
        off += (bytes + 255) & ~(size_t)255;
        return p;
    };
    float* phi     = (float*)alloc((size_t)NN * 15 * 4);
    float* delta   = (float*)alloc((size_t)NN * 64 * 4);
    float* hid     = (float*)alloc((size_t)NN * 256 * 4);   // hid, then reused for h
    float* csr_a   = (float*)alloc((size_t)EE * 4 * 4);
    int*   csr_src = (int*)alloc((size_t)EE * 4);
    int*   deg     = (int*)alloc((size_t)NN * 4);
    int*   offs    = (int*)alloc((size_t)(NN + 1) * 4);
    int*   cursor  = (int*)alloc((size_t)NN * 4);
    float* tnorm   = (float*)alloc(64 * 4);
    float* part    = (float*)alloc(512 * 4);

    hipMemsetAsync(deg, 0, (size_t)NN * 4, stream);

    tnorm_lsep_k<<<1, 64, 0, stream>>>(tilde_phi, tnorm, out + (size_t)NN * OUTD);

    dim3 blk(256);
    // phi = e_l @ W_phi          [N,128]x[128,15]
    gemm_k<128, false, false><<<dim3(782, 1), blk, 0, stream>>>(e_l, W_phi, nullptr, phi, NN, 15);
    // hid = relu(e_l @ W1^T + b1)  [N,128]x[128,256]
    gemm_k<128, true, true><<<dim3(782, 4), blk, 0, stream>>>(e_l, W1, b1, hid, NN, 256);
    // delta = hid @ W2^T + b2    [N,256]x[256,64]
    gemm_k<256, true, false><<<dim3(782, 1), blk, 0, stream>>>(hid, W2, b2, delta, NN, 64);
    // h = h_l @ W                [N,256]x[256,256]  (into hid buffer; hid now dead)
    gemm_k<256, false, false><<<dim3(782, 4), blk, 0, stream>>>(h_l, W, nullptr, hid, NN, 256);

    // CSR build
    degree_k<<<3125, 256, 0, stream>>>(dst, deg);
    scan_k<<<1, 1024, 0, stream>>>(deg, offs, cursor, NN);

    // edge logits + scatter into CSR
    edge_k<<<3125, 256, 0, stream>>>(phi, delta, tnorm, src, dst, cursor, csr_src,
                                     (float4*)csr_a);

    // per-dst softmax + aggregation + normalize
    aggregate_k<<<12500, 256, 0, stream>>>(offs, csr_src, (const float4*)csr_a, hid,
                                           bias, out);

    // l_focus
    lfocus_partial_k<<<512, 256, 0, stream>>>(delta, part, NN * 64);
    lfocus_final_k<<<1, 256, 0, stream>>>(part, 512, out + (size_t)NN * OUTD + 1);
}

// Round 2
// 548.634 us; speedup vs baseline: 1.2575x; 1.2575x over previous
//
#include <hip/hip_runtime.h>
#include <math.h>

#define NN 50000
#define EE 800000
#define RAWD 128
#define HIDD 256
#define OUTD 64
#define KK 4
#define PHID 16

typedef __attribute__((ext_vector_type(8))) short short8;
typedef __attribute__((ext_vector_type(4))) float f32x4;

__device__ inline float b2f(unsigned short u) {
    union { unsigned i; float f; } v; v.i = ((unsigned)u) << 16; return v.f;
}
__device__ inline unsigned short f2b(float f) {
    unsigned u = __float_as_uint(f);
    unsigned r = (u + 0x7FFFu + ((u >> 16) & 1u)) >> 16;   // RNE
    return (unsigned short)r;
}

// ---------------------------------------------------------------------------
// casts
// ---------------------------------------------------------------------------
__global__ void cast_bf16_k(const float* __restrict__ in, unsigned short* __restrict__ out,
                            int count4) {
    int i = blockIdx.x * 256 + threadIdx.x;
    if (i >= count4) return;
    float4 v = ((const float4*)in)[i];
    ushort4 o;
    o.x = f2b(v.x); o.y = f2b(v.y); o.z = f2b(v.z); o.w = f2b(v.w);
    ((ushort4*)out)[i] = o;
}

// Wt[c][r] = W[r][c], rows c >= C are zero-padded (Cpad rows)
__global__ void tcast_k(const float* __restrict__ in, unsigned short* __restrict__ out,
                        int R, int C, int Cpad) {
    int i = blockIdx.x * 256 + threadIdx.x;
    if (i >= R * Cpad) return;
    int c = i / R, r = i % R;
    out[(size_t)c * R + r] = (c < C) ? f2b(in[(size_t)r * C + c]) : (unsigned short)0;
}

// ---------------------------------------------------------------------------
// bf16 MFMA GEMM: C[nrows, BN*gridDim.y] = act(A @ Bt^T + bias)
//   A  : [nrows][KD] bf16 row-major
//   Bt : [Ncols][KD] bf16 row-major  (i.e. B' pre-transposed, n-major)
// BM=128, BK=32, 256 threads (4 waves). Wave grid WMxWN, frag grid AMxAN.
// ---------------------------------------------------------------------------
template <int KD, int BN, int WN_WAVES, int AM, int AN, bool RELU, bool OUT_BF16>
__global__ __launch_bounds__(256) void mgemm_k(const unsigned short* __restrict__ A,
                                               const unsigned short* __restrict__ Bt,
                                               const float* __restrict__ bias_vec,
                                               void* __restrict__ Cout,
                                               int nrows, int ldc) {
    const int BM = 128, BK = 32;
    __shared__ __align__(16) unsigned short As[BM * BK];
    __shared__ __align__(16) unsigned short Bs[BN * BK];
    const int tid = threadIdx.x;
    const int w = tid >> 6, l = tid & 63;
    const int row0 = blockIdx.x * BM;
    const int col0 = blockIdx.y * BN;
    const int wr = w / WN_WAVES, wc = w % WN_WAVES;
    const int wm0 = wr * (AM * 16), wn0 = wc * (AN * 16);
    const int l15 = l & 15, l4 = l >> 4;

    const int A_PER = (BM * 4) / 256;          // 2
    const int B_CHUNKS = BN * 4;               // 512 / 256 / 64

    uint4 areg[A_PER];
    uint4 breg[(B_CHUNKS + 255) / 256];

    f32x4 acc[AM][AN];
    #pragma unroll
    for (int m = 0; m < AM; ++m)
        #pragma unroll
        for (int n = 0; n < AN; ++n)
            acc[m][n] = (f32x4){0.f, 0.f, 0.f, 0.f};

    auto loadTiles = [&](int k0) {
        #pragma unroll
        for (int i = 0; i < A_PER; ++i) {
            int idx = i * 256 + tid;
            int r = idx >> 2, c = idx & 3;
            int gr = row0 + r; if (gr >= nrows) gr = nrows - 1;
            areg[i] = *(const uint4*)&A[(size_t)gr * KD + k0 + c * 8];
        }
        if (B_CHUNKS >= 256) {
            #pragma unroll
            for (int i = 0; i < B_CHUNKS / 256; ++i) {
                int idx = i * 256 + tid;
                int r = idx >> 2, c = idx & 3;
                breg[i] = *(const uint4*)&Bt[(size_t)(col0 + r) * KD + k0 + c * 8];
            }
        } else if (tid < B_CHUNKS) {
            int r = tid >> 2, c = tid & 3;
            breg[0] = *(const uint4*)&Bt[(size_t)(col0 + r) * KD + k0 + c * 8];
        }
    };
    auto writeTiles = [&]() {
        #pragma unroll
        for (int i = 0; i < A_PER; ++i) {
            int idx = i * 256 + tid;
            *(uint4*)&As[idx * 8] = areg[i];
        }
        if (B_CHUNKS >= 256) {
            #pragma unroll
            for (int i = 0; i < B_CHUNKS / 256; ++i) {
                int idx = i * 256 + tid;
                *(uint4*)&Bs[idx * 8] = breg[i];
            }
        } else if (tid < B_CHUNKS) {
            *(uint4*)&Bs[tid * 8] = breg[0];
        }
    };

    loadTiles(0);
    const int NT = KD / BK;
    for (int t = 0; t < NT; ++t) {
        __syncthreads();                 // previous iteration's LDS reads done
        writeTiles();
        __syncthreads();
        if (t + 1 < NT) loadTiles((t + 1) * BK);   // prefetch overlaps MFMA
        short8 af[AM], bfr[AN];
        #pragma unroll
        for (int m = 0; m < AM; ++m)
            af[m] = *(const short8*)&As[(wm0 + m * 16 + l15) * BK + l4 * 8];
        #pragma unroll
        for (int n = 0; n < AN; ++n)
            bfr[n] = *(const short8*)&Bs[(wn0 + n * 16 + l15) * BK + l4 * 8];
        #pragma unroll
        for (int m = 0; m < AM; ++m)
            #pragma unroll
            for (int n = 0; n < AN; ++n)
                acc[m][n] = __builtin_amdgcn_mfma_f32_16x16x32_bf16(af[m], bfr[n], acc[m][n], 0, 0, 0);
    }

    // epilogue: C/D layout col=lane&15, row=(lane>>4)*4+reg  [m89/m91]
    #pragma unroll
    for (int m = 0; m < AM; ++m) {
        #pragma unroll
        for (int n = 0; n < AN; ++n) {
            int gc = col0 + wn0 + n * 16 + l15;
            float bv = bias_vec ? bias_vec[gc] : 0.f;
            #pragma unroll
            for (int r = 0; r < 4; ++r) {
                int gr = row0 + wm0 + m * 16 + l4 * 4 + r;
                if (gr >= nrows) continue;
                float v = acc[m][n][r] + bv;
                if (RELU) v = fmaxf(v, 0.f);
                if (OUT_BF16)
                    ((unsigned short*)Cout)[(size_t)gr * ldc + gc] = f2b(v);
                else
                    ((float*)Cout)[(size_t)gr * ldc + gc] = v;
            }
        }
    }
}

// ---------------------------------------------------------------------------
// tilde_norm + l_sep
// ---------------------------------------------------------------------------
__global__ void tnorm_lsep_k(const float* __restrict__ tilde_phi,
                             float* __restrict__ tnorm,
                             float* __restrict__ lsep_out) {
    __shared__ float tn[KK][PHID];
    int t = threadIdx.x;
    if (t < KK * PHID) {
        float v = tilde_phi[t];
        float sq = v * v;
        #pragma unroll
        for (int s = 8; s; s >>= 1) sq += __shfl_xor(sq, s, 16);
        float tnv = v / sqrtf(sq);
        tn[t >> 4][t & 15] = tnv;
        tnorm[t] = tnv;
    }
    __syncthreads();
    if (t == 0) {
        float tot = 0.f;
        for (int i = 0; i < KK; ++i)
            for (int j = 0; j < KK; ++j) {
                float s2 = 0.f;
                for (int p = 0; p < PHID; ++p) {
                    float df = tn[i][p] - tn[j][p];
                    s2 += df * df;
                }
                tot += s2;
            }
        lsep_out[0] = tot / (float)KK;
    }
}

// ---------------------------------------------------------------------------
__global__ void degree_k(const int* __restrict__ dst, int* __restrict__ deg) {
    int e = blockIdx.x * 256 + threadIdx.x;
    if (e < EE) atomicAdd(&deg[dst[e]], 1);
}

// chunked single-block scan: thread t owns [t*C,(t+1)*C)
__global__ __launch_bounds__(1024) void scan_k(const int* __restrict__ deg,
                                               int* __restrict__ offs,
                                               int* __restrict__ cursor, int n) {
    __shared__ int wsum_s[16];
    __shared__ int wexc_s[16];
    int t = threadIdx.x;
    int lane = t & 63, wid = t >> 6;
    const int C = (n + 1023) >> 10;
    int beg = t * C;
    int end = beg + C; if (end > n) end = n;
    int s = 0;
    for (int i = beg; i < end; ++i) s += deg[i];
    int x = s;
    #pragma unroll
    for (int d = 1; d < 64; d <<= 1) { int v = __shfl_up(x, d); if (lane >= d) x += v; }
    if (lane == 63) wsum_s[wid] = x;
    __syncthreads();
    if (t < 16) {
        int wv = wsum_s[t];
        int wi = wv;
        #pragma unroll
        for (int d = 1; d < 16; d <<= 1) { int v = __shfl_up(wi, d); if (t >= d) wi += v; }
        wexc_s[t] = wi - wv;
    }
    __syncthreads();
    int run = (x - s) + wexc_s[wid];
    if (t == 0) offs[0] = 0;
    for (int i = beg; i < end; ++i) {
        cursor[i] = run;
        run += deg[i];
        offs[i + 1] = run;
    }
}

// ---------------------------------------------------------------------------
// edge pass: dist -> normalized -> 4 logits, scatter into CSR slot of dst
// phi has stride 16 (col 15 is zero).
// ---------------------------------------------------------------------------
__global__ __launch_bounds__(256) void edge_k(const float* __restrict__ phi,
                                              const float* __restrict__ delta,
                                              const float* __restrict__ tnorm,
                                              const int* __restrict__ src,
                                              const int* __restrict__ dst,
                                              int* __restrict__ cursor,
                                              int* __restrict__ csr_src,
                                              float4* __restrict__ csr_a) {
    __shared__ float tn[KK * PHID];
    if (threadIdx.x < KK * PHID) tn[threadIdx.x] = tnorm[threadIdx.x];
    __syncthreads();
    int e = blockIdx.x * 256 + threadIdx.x;
    if (e >= EE) return;
    int s = src[e], d = dst[e];
    const float4* ps4 = (const float4*)(phi + (size_t)s * 16);
    const float4* pd4 = (const float4*)(phi + (size_t)d * 16);
    float dv[16];
    #pragma unroll
    for (int q = 0; q < 4; ++q) {
        float4 a = ps4[q], b = pd4[q];
        dv[q * 4 + 0] = a.x - b.x;
        dv[q * 4 + 1] = a.y - b.y;
        dv[q * 4 + 2] = a.z - b.z;
        dv[q * 4 + 3] = a.w - b.w;
    }
    bool allz = true;
    float nrm2 = 0.f;
    #pragma unroll
    for (int p = 0; p < 15; ++p) {
        allz = allz && (dv[p] == 0.f);
        nrm2 += dv[p] * dv[p];
    }
    dv[15] = allz ? 1.f : 0.f;
    nrm2 += dv[15];
    float inv = 1.f / fmaxf(sqrtf(nrm2), 1e-8f);
    const float* dl = delta + (size_t)d * 64;
    float res[4];
    #pragma unroll
    for (int k = 0; k < 4; ++k) {
        const float4* dk = (const float4*)(dl + k * 16);
        float sacc = 0.f;
        #pragma unroll
        for (int q = 0; q < 4; ++q) {
            float4 tv = dk[q];
            sacc += dv[q * 4 + 0] * (tn[k * 16 + q * 4 + 0] + tv.x);
            sacc += dv[q * 4 + 1] * (tn[k * 16 + q * 4 + 1] + tv.y);
            sacc += dv[q * 4 + 2] * (tn[k * 16 + q * 4 + 2] + tv.z);
            sacc += dv[q * 4 + 3] * (tn[k * 16 + q * 4 + 3] + tv.w);
        }
        res[k] = sacc * inv;
    }
    int pos = atomicAdd(&cursor[d], 1);
    csr_src[pos] = s;
    csr_a[pos] = make_float4(res[0], res[1], res[2], res[3]);
}

// ---------------------------------------------------------------------------
// per-dst: softmax denom + weighted aggregation of bf16 h[src] + row-normalize
// one wave per node; lane = output channel
// ---------------------------------------------------------------------------
__global__ __launch_bounds__(256) void aggregate_k(const int* __restrict__ offs,
                                                   const int* __restrict__ csr_src,
                                                   const float4* __restrict__ csr_a,
                                                   const unsigned short* __restrict__ h,
                                                   const float* __restrict__ bias,
                                                   float* __restrict__ out) {
    int wave = threadIdx.x >> 6;
    int lane = threadIdx.x & 63;
    int n = blockIdx.x * 4 + wave;
    if (n >= NN) return;
    int beg = offs[n], end = offs[n + 1];

    float d0 = 0.f, d1 = 0.f, d2 = 0.f, d3 = 0.f;
    for (int p = beg + lane; p < end; p += 64) {
        float4 av = csr_a[p];
        d0 += __expf(av.x); d1 += __expf(av.y);
        d2 += __expf(av.z); d3 += __expf(av.w);
    }
    #pragma unroll
    for (int s = 32; s; s >>= 1) {
        d0 += __shfl_xor(d0, s); d1 += __shfl_xor(d1, s);
        d2 += __shfl_xor(d2, s); d3 += __shfl_xor(d3, s);
    }
    float i0 = (d0 > 0.f) ? 1.f / d0 : 0.f;
    float i1 = (d1 > 0.f) ? 1.f / d1 : 0.f;
    float i2 = (d2 > 0.f) ? 1.f / d2 : 0.f;
    float i3 = (d3 > 0.f) ? 1.f / d3 : 0.f;

    float acc = 0.f;
    for (int p = beg; p < end; ++p) {
        float4 av = csr_a[p];
        int sn = csr_src[p];
        float w0 = __expf(av.x) * i0;
        float w1 = __expf(av.y) * i1;
        float w2 = __expf(av.z) * i2;
        float w3 = __expf(av.w) * i3;
        const unsigned short* hr = h + (size_t)sn * 256;
        acc += b2f(hr[lane]) * w0 + b2f(hr[64 + lane]) * w1 +
               b2f(hr[128 + lane]) * w2 + b2f(hr[192 + lane]) * w3;
    }
    acc += bias[lane];
    float nr = acc * acc;
    #pragma unroll
    for (int s = 32; s; s >>= 1) nr += __shfl_xor(nr, s);
    float invn = 1.f / fmaxf(sqrtf(nr), 1e-8f);
    out[(size_t)n * 64 + lane] = acc * invn;
}

// ---------------------------------------------------------------------------
__global__ void lfocus_partial_k(const float* __restrict__ delta,
                                 float* __restrict__ part, int count) {
    __shared__ float sd[256];
    float s = 0.f;
    for (int i = blockIdx.x * 256 + threadIdx.x; i < count; i += gridDim.x * 256) {
        float v = delta[i];
        s += v * v;
    }
    sd[threadIdx.x] = s;
    __syncthreads();
    for (int st = 128; st; st >>= 1) {
        if (threadIdx.x < st) sd[threadIdx.x] += sd[threadIdx.x + st];
        __syncthreads();
    }
    if (threadIdx.x == 0) part[blockIdx.x] = sd[0];
}

__global__ void lfocus_final_k(const float* __restrict__ part, int nb,
                               float* __restrict__ outp) {
    __shared__ float sd[256];
    float s = 0.f;
    for (int i = threadIdx.x; i < nb; i += 256) s += part[i];
    sd[threadIdx.x] = s;
    __syncthreads();
    for (int st = 128; st; st >>= 1) {
        if (threadIdx.x < st) sd[threadIdx.x] += sd[threadIdx.x + st];
        __syncthreads();
    }
    if (threadIdx.x == 0) outp[0] = sd[0] / (float)((size_t)NN * KK);
}

// ---------------------------------------------------------------------------
extern "C" void kernel_launch(void* const* d_in, const int* in_sizes, int n_in,
                              void* d_out, int out_size, void* d_ws, size_t ws_size,
                              hipStream_t stream) {
    const float* h_l       = (const float*)d_in[0];
    const float* e_l       = (const float*)d_in[1];
    const int*   src       = (const int*)d_in[2];
    const int*   dst       = (const int*)d_in[3];
    const float* W_phi     = (const float*)d_in[4];
    const float* W1        = (const float*)d_in[5];
    const float* b1        = (const float*)d_in[6];
    const float* W2        = (const float*)d_in[7];
    const float* b2        = (const float*)d_in[8];
    const float* tilde_phi = (const float*)d_in[9];
    const float* W         = (const float*)d_in[10];
    const float* bias      = (const float*)d_in[11];
    float* out = (float*)d_out;

    char* ws = (char*)d_ws;
    size_t off = 0;
    auto alloc = [&](size_t bytes) -> char* {
        char* p = ws + off;
        off += (bytes + 255) & ~(size_t)255;
        return p;
    };
    float*          phi     = (float*)alloc((size_t)NN * 16 * 4);
    float*          delta   = (float*)alloc((size_t)NN * 64 * 4);
    unsigned short* h_bf    = (unsigned short*)alloc((size_t)NN * 256 * 2);
    unsigned short* hid_bf  = (unsigned short*)alloc((size_t)NN * 256 * 2);
    unsigned short* e_bf    = (unsigned short*)alloc((size_t)NN * 128 * 2);
    unsigned short* hl_bf   = (unsigned short*)alloc((size_t)NN * 256 * 2);
    float*          csr_a   = (float*)alloc((size_t)EE * 4 * 4);
    int*            csr_src = (int*)alloc((size_t)EE * 4);
    int*            deg     = (int*)alloc((size_t)NN * 4);
    int*            offs    = (int*)alloc((size_t)(NN + 1) * 4);
    int*            cursor  = (int*)alloc((size_t)NN * 4);
    unsigned short* W_t     = (unsigned short*)alloc(256 * 256 * 2);
    unsigned short* W1_bf   = (unsigned short*)alloc(256 * 128 * 2);
    unsigned short* W2_bf   = (unsigned short*)alloc(64 * 256 * 2);
    unsigned short* Wphi_t  = (unsigned short*)alloc(16 * 128 * 2);
    float*          tnorm   = (float*)alloc(64 * 4);
    float*          part    = (float*)alloc(512 * 4);

    hipMemsetAsync(deg, 0, (size_t)NN * 4, stream);

    tnorm_lsep_k<<<1, 64, 0, stream>>>(tilde_phi, tnorm, out + (size_t)NN * OUTD);

    // casts
    cast_bf16_k<<<(NN * 128 / 4 + 255) / 256, 256, 0, stream>>>(e_l, e_bf, NN * 128 / 4);
    cast_bf16_k<<<(NN * 256 / 4 + 255) / 256, 256, 0, stream>>>(h_l, hl_bf, NN * 256 / 4);
    cast_bf16_k<<<(256 * 128 / 4 + 255) / 256, 256, 0, stream>>>(W1, W1_bf, 256 * 128 / 4);
    cast_bf16_k<<<(64 * 256 / 4 + 255) / 256, 256, 0, stream>>>(W2, W2_bf, 64 * 256 / 4);
    tcast_k<<<(256 * 256 + 255) / 256, 256, 0, stream>>>(W, W_t, 256, 256, 256);
    tcast_k<<<(128 * 16 + 255) / 256, 256, 0, stream>>>(W_phi, Wphi_t, 128, 15, 16);

    const int MB = (NN + 127) / 128;   // 391
    // phi = e_l @ W_phi (padded to 16 cols), stride 16
    mgemm_k<128, 16, 1, 2, 1, false, false><<<dim3(MB, 1), 256, 0, stream>>>(
        e_bf, Wphi_t, nullptr, phi, NN, 16);
    // hid = relu(e_l @ W1^T + b1) -> bf16
    mgemm_k<128, 128, 2, 4, 4, true, true><<<dim3(MB, 2), 256, 0, stream>>>(
        e_bf, W1_bf, b1, hid_bf, NN, 256);
    // delta = hid @ W2^T + b2 -> f32
    mgemm_k<256, 64, 1, 2, 4, false, false><<<dim3(MB, 1), 256, 0, stream>>>(
        hid_bf, W2_bf, b2, delta, NN, 64);
    // h = h_l @ W -> bf16
    mgemm_k<256, 128, 2, 4, 4, false, true><<<dim3(MB, 2), 256, 0, stream>>>(
        hl_bf, W_t, nullptr, h_bf, NN, 256);

    // CSR build
    degree_k<<<3125, 256, 0, stream>>>(dst, deg);
    scan_k<<<1, 1024, 0, stream>>>(deg, offs, cursor, NN);

    // edge logits + scatter into CSR
    edge_k<<<3125, 256, 0, stream>>>(phi, delta, tnorm, src, dst, cursor, csr_src,
                                     (float4*)csr_a);

    // per-dst softmax + aggregation + normalize
    aggregate_k<<<12500, 256, 0, stream>>>(offs, csr_src, (const float4*)csr_a, h_bf,
                                           bias, out);

    // l_focus
    lfocus_partial_k<<<512, 256, 0, stream>>>(delta, part, NN * 64);
    lfocus_final_k<<<1, 256, 0, stream>>>(part, 512, out + (size_t)NN * OUTD + 1);
}

// Round 3
// 449.180 us; speedup vs baseline: 1.5359x; 1.2214x over previous
//
#include <hip/hip_runtime.h>
#include <math.h>

#define NN 50000
#define EE 800000
#define RAWD 128
#define HIDD 256
#define OUTD 64
#define KK 4
#define PHID 16

typedef __attribute__((ext_vector_type(8))) short short8;
typedef __attribute__((ext_vector_type(4))) float f32x4;

__device__ inline float b2f(unsigned short u) {
    union { unsigned i; float f; } v; v.i = ((unsigned)u) << 16; return v.f;
}
__device__ inline unsigned short f2b(float f) {
    unsigned u = __float_as_uint(f);
    unsigned r = (u + 0x7FFFu + ((u >> 16) & 1u)) >> 16;   // RNE
    return (unsigned short)r;
}

// ---------------------------------------------------------------------------
// casts
// ---------------------------------------------------------------------------
__global__ void cast_bf16_k(const float* __restrict__ in, unsigned short* __restrict__ out,
                            int count4) {
    int i = blockIdx.x * 256 + threadIdx.x;
    if (i >= count4) return;
    float4 v = ((const float4*)in)[i];
    ushort4 o;
    o.x = f2b(v.x); o.y = f2b(v.y); o.z = f2b(v.z); o.w = f2b(v.w);
    ((ushort4*)out)[i] = o;
}

// Wt[c][r] = W[r][c], rows c >= C are zero-padded (Cpad rows)
__global__ void tcast_k(const float* __restrict__ in, unsigned short* __restrict__ out,
                        int R, int C, int Cpad) {
    int i = blockIdx.x * 256 + threadIdx.x;
    if (i >= R * Cpad) return;
    int c = i / R, r = i % R;
    out[(size_t)c * R + r] = (c < C) ? f2b(in[(size_t)r * C + c]) : (unsigned short)0;
}

// ---------------------------------------------------------------------------
// bf16 MFMA GEMM: C[nrows, BN*gridDim.y] = act(A @ Bt^T + bias)
// BM=128, BK=32, 256 threads (4 waves). Wave grid 2xWN_WAVES, frag grid AMxAN.
// ---------------------------------------------------------------------------
template <int KD, int BN, int WN_WAVES, int AM, int AN, bool RELU, bool OUT_BF16>
__global__ __launch_bounds__(256) void mgemm_k(const unsigned short* __restrict__ A,
                                               const unsigned short* __restrict__ Bt,
                                               const float* __restrict__ bias_vec,
                                               void* __restrict__ Cout,
                                               int nrows, int ldc) {
    const int BM = 128, BK = 32;
    __shared__ __align__(16) unsigned short As[BM * BK];
    __shared__ __align__(16) unsigned short Bs[BN * BK];
    const int tid = threadIdx.x;
    const int w = tid >> 6, l = tid & 63;
    const int row0 = blockIdx.x * BM;
    const int col0 = blockIdx.y * BN;
    const int wr = w / WN_WAVES, wc = w % WN_WAVES;
    const int wm0 = wr * (AM * 16), wn0 = wc * (AN * 16);
    const int l15 = l & 15, l4 = l >> 4;

    const int A_PER = (BM * 4) / 256;          // 2
    const int B_CHUNKS = BN * 4;               // 512 / 256 / 64

    uint4 areg[A_PER];
    uint4 breg[(B_CHUNKS + 255) / 256];

    f32x4 acc[AM][AN];
    #pragma unroll
    for (int m = 0; m < AM; ++m)
        #pragma unroll
        for (int n = 0; n < AN; ++n)
            acc[m][n] = (f32x4){0.f, 0.f, 0.f, 0.f};

    auto loadTiles = [&](int k0) {
        #pragma unroll
        for (int i = 0; i < A_PER; ++i) {
            int idx = i * 256 + tid;
            int r = idx >> 2, c = idx & 3;
            int gr = row0 + r; if (gr >= nrows) gr = nrows - 1;
            areg[i] = *(const uint4*)&A[(size_t)gr * KD + k0 + c * 8];
        }
        if (B_CHUNKS >= 256) {
            #pragma unroll
            for (int i = 0; i < B_CHUNKS / 256; ++i) {
                int idx = i * 256 + tid;
                int r = idx >> 2, c = idx & 3;
                breg[i] = *(const uint4*)&Bt[(size_t)(col0 + r) * KD + k0 + c * 8];
            }
        } else if (tid < B_CHUNKS) {
            int r = tid >> 2, c = tid & 3;
            breg[0] = *(const uint4*)&Bt[(size_t)(col0 + r) * KD + k0 + c * 8];
        }
    };
    auto writeTiles = [&]() {
        #pragma unroll
        for (int i = 0; i < A_PER; ++i) {
            int idx = i * 256 + tid;
            *(uint4*)&As[idx * 8] = areg[i];
        }
        if (B_CHUNKS >= 256) {
            #pragma unroll
            for (int i = 0; i < B_CHUNKS / 256; ++i) {
                int idx = i * 256 + tid;
                *(uint4*)&Bs[idx * 8] = breg[i];
            }
        } else if (tid < B_CHUNKS) {
            *(uint4*)&Bs[tid * 8] = breg[0];
        }
    };

    loadTiles(0);
    const int NT = KD / BK;
    for (int t = 0; t < NT; ++t) {
        __syncthreads();
        writeTiles();
        __syncthreads();
        if (t + 1 < NT) loadTiles((t + 1) * BK);
        short8 af[AM], bfr[AN];
        #pragma unroll
        for (int m = 0; m < AM; ++m)
            af[m] = *(const short8*)&As[(wm0 + m * 16 + l15) * BK + l4 * 8];
        #pragma unroll
        for (int n = 0; n < AN; ++n)
            bfr[n] = *(const short8*)&Bs[(wn0 + n * 16 + l15) * BK + l4 * 8];
        #pragma unroll
        for (int m = 0; m < AM; ++m)
            #pragma unroll
            for (int n = 0; n < AN; ++n)
                acc[m][n] = __builtin_amdgcn_mfma_f32_16x16x32_bf16(af[m], bfr[n], acc[m][n], 0, 0, 0);
    }

    // C/D layout: col=lane&15, row=(lane>>4)*4+reg
    #pragma unroll
    for (int m = 0; m < AM; ++m) {
        #pragma unroll
        for (int n = 0; n < AN; ++n) {
            int gc = col0 + wn0 + n * 16 + l15;
            float bv = bias_vec ? bias_vec[gc] : 0.f;
            #pragma unroll
            for (int r = 0; r < 4; ++r) {
                int gr = row0 + wm0 + m * 16 + l4 * 4 + r;
                if (gr >= nrows) continue;
                float v = acc[m][n][r] + bv;
                if (RELU) v = fmaxf(v, 0.f);
                if (OUT_BF16)
                    ((unsigned short*)Cout)[(size_t)gr * ldc + gc] = f2b(v);
                else
                    ((float*)Cout)[(size_t)gr * ldc + gc] = v;
            }
        }
    }
}

// ---------------------------------------------------------------------------
// tilde_norm + l_sep
// ---------------------------------------------------------------------------
__global__ void tnorm_lsep_k(const float* __restrict__ tilde_phi,
                             float* __restrict__ tnorm,
                             float* __restrict__ lsep_out) {
    __shared__ float tn[KK][PHID];
    int t = threadIdx.x;
    if (t < KK * PHID) {
        float v = tilde_phi[t];
        float sq = v * v;
        #pragma unroll
        for (int s = 8; s; s >>= 1) sq += __shfl_xor(sq, s, 16);
        float tnv = v / sqrtf(sq);
        tn[t >> 4][t & 15] = tnv;
        tnorm[t] = tnv;
    }
    __syncthreads();
    if (t == 0) {
        float tot = 0.f;
        for (int i = 0; i < KK; ++i)
            for (int j = 0; j < KK; ++j) {
                float s2 = 0.f;
                for (int p = 0; p < PHID; ++p) {
                    float df = tn[i][p] - tn[j][p];
                    s2 += df * df;
                }
                tot += s2;
            }
        lsep_out[0] = tot / (float)KK;
    }
}

// ---------------------------------------------------------------------------
__global__ void degree_k(const int* __restrict__ dst, int* __restrict__ deg) {
    int e = blockIdx.x * 256 + threadIdx.x;
    if (e < EE) atomicAdd(&deg[dst[e]], 1);
}

// ---------------------------------------------------------------------------
// device-wide scan over deg[NN], 256 elems/block, 3 dispatches
// ---------------------------------------------------------------------------
#define SCAN_NB ((NN + 255) / 256)   // 196

__global__ __launch_bounds__(256) void scan_partial_k(const int* __restrict__ deg,
                                                      int* __restrict__ bsum) {
    __shared__ int ws_[4];
    int i = blockIdx.x * 256 + threadIdx.x;
    int v = (i < NN) ? deg[i] : 0;
    int x = v;
    #pragma unroll
    for (int s = 32; s; s >>= 1) x += __shfl_xor(x, s);
    if ((threadIdx.x & 63) == 0) ws_[threadIdx.x >> 6] = x;
    __syncthreads();
    if (threadIdx.x == 0) bsum[blockIdx.x] = ws_[0] + ws_[1] + ws_[2] + ws_[3];
}

__global__ __launch_bounds__(256) void scan_bsum_k(int* __restrict__ bsum) {
    // exclusive scan of SCAN_NB (<=256) values, single block
    __shared__ int sd[256];
    int t = threadIdx.x;
    int v = (t < SCAN_NB) ? bsum[t] : 0;
    sd[t] = v;
    __syncthreads();
    for (int s = 1; s < 256; s <<= 1) {
        int u = (t >= s) ? sd[t - s] : 0;
        __syncthreads();
        sd[t] += u;
        __syncthreads();
    }
    if (t < SCAN_NB) bsum[t] = sd[t] - v;   // exclusive
}

__global__ __launch_bounds__(256) void scan_scatter_k(const int* __restrict__ deg,
                                                      const int* __restrict__ bsum,
                                                      int* __restrict__ offs,
                                                      int* __restrict__ cursor) {
    __shared__ int wexc[4];
    int i = blockIdx.x * 256 + threadIdx.x;
    int lane = threadIdx.x & 63, wid = threadIdx.x >> 6;
    int v = (i < NN) ? deg[i] : 0;
    int x = v;
    #pragma unroll
    for (int d = 1; d < 64; d <<= 1) { int u = __shfl_up(x, d); if (lane >= d) x += u; }
    // x = inclusive within wave
    if (lane == 63) wexc[wid] = x;
    __syncthreads();
    if (threadIdx.x == 0) {
        int a = wexc[0], b = wexc[1], c = wexc[2];
        wexc[0] = 0; wexc[1] = a; wexc[2] = a + b; wexc[3] = a + b + c;
    }
    __syncthreads();
    int excl = (x - v) + wexc[wid] + bsum[blockIdx.x];
    if (i < NN) {
        cursor[i] = excl;
        offs[i + 1] = excl + v;
        if (i == 0) offs[0] = 0;
    }
}

// ---------------------------------------------------------------------------
// edge pass: dist -> normalized -> 4 logits, scatter into CSR slot of dst
// ---------------------------------------------------------------------------
__global__ __launch_bounds__(256) void edge_k(const float* __restrict__ phi,
                                              const float* __restrict__ delta,
                                              const float* __restrict__ tnorm,
                                              const int* __restrict__ src,
                                              const int* __restrict__ dst,
                                              int* __restrict__ cursor,
                                              int* __restrict__ csr_src,
                                              float4* __restrict__ csr_a) {
    __shared__ float tn[KK * PHID];
    if (threadIdx.x < KK * PHID) tn[threadIdx.x] = tnorm[threadIdx.x];
    __syncthreads();
    int e = blockIdx.x * 256 + threadIdx.x;
    if (e >= EE) return;
    int s = src[e], d = dst[e];
    const float4* ps4 = (const float4*)(phi + (size_t)s * 16);
    const float4* pd4 = (const float4*)(phi + (size_t)d * 16);
    float dv[16];
    #pragma unroll
    for (int q = 0; q < 4; ++q) {
        float4 a = ps4[q], b = pd4[q];
        dv[q * 4 + 0] = a.x - b.x;
        dv[q * 4 + 1] = a.y - b.y;
        dv[q * 4 + 2] = a.z - b.z;
        dv[q * 4 + 3] = a.w - b.w;
    }
    bool allz = true;
    float nrm2 = 0.f;
    #pragma unroll
    for (int p = 0; p < 15; ++p) {
        allz = allz && (dv[p] == 0.f);
        nrm2 += dv[p] * dv[p];
    }
    dv[15] = allz ? 1.f : 0.f;
    nrm2 += dv[15];
    float inv = 1.f / fmaxf(sqrtf(nrm2), 1e-8f);
    const float* dl = delta + (size_t)d * 64;
    float res[4];
    #pragma unroll
    for (int k = 0; k < 4; ++k) {
        const float4* dk = (const float4*)(dl + k * 16);
        float sacc = 0.f;
        #pragma unroll
        for (int q = 0; q < 4; ++q) {
            float4 tv = dk[q];
            sacc += dv[q * 4 + 0] * (tn[k * 16 + q * 4 + 0] + tv.x);
            sacc += dv[q * 4 + 1] * (tn[k * 16 + q * 4 + 1] + tv.y);
            sacc += dv[q * 4 + 2] * (tn[k * 16 + q * 4 + 2] + tv.z);
            sacc += dv[q * 4 + 3] * (tn[k * 16 + q * 4 + 3] + tv.w);
        }
        res[k] = sacc * inv;
    }
    int pos = atomicAdd(&cursor[d], 1);
    csr_src[pos] = s;
    csr_a[pos] = make_float4(res[0], res[1], res[2], res[3]);
}

// ---------------------------------------------------------------------------
// per-dst: softmax denom + weighted aggregation of bf16 h[src] + row-normalize
// ---------------------------------------------------------------------------
__global__ __launch_bounds__(256) void aggregate_k(const int* __restrict__ offs,
                                                   const int* __restrict__ csr_src,
                                                   const float4* __restrict__ csr_a,
                                                   const unsigned short* __restrict__ h,
                                                   const float* __restrict__ bias,
                                                   float* __restrict__ out) {
    int wave = threadIdx.x >> 6;
    int lane = threadIdx.x & 63;
    int n = blockIdx.x * 4 + wave;
    if (n >= NN) return;
    int beg = offs[n], end = offs[n + 1];

    float d0 = 0.f, d1 = 0.f, d2 = 0.f, d3 = 0.f;
    for (int p = beg + lane; p < end; p += 64) {
        float4 av = csr_a[p];
        d0 += __expf(av.x); d1 += __expf(av.y);
        d2 += __expf(av.z); d3 += __expf(av.w);
    }
    #pragma unroll
    for (int s = 32; s; s >>= 1) {
        d0 += __shfl_xor(d0, s); d1 += __shfl_xor(d1, s);
        d2 += __shfl_xor(d2, s); d3 += __shfl_xor(d3, s);
    }
    float i0 = (d0 > 0.f) ? 1.f / d0 : 0.f;
    float i1 = (d1 > 0.f) ? 1.f / d1 : 0.f;
    float i2 = (d2 > 0.f) ? 1.f / d2 : 0.f;
    float i3 = (d3 > 0.f) ? 1.f / d3 : 0.f;

    float acc = 0.f;
    for (int p = beg; p < end; ++p) {
        float4 av = csr_a[p];
        int sn = csr_src[p];
        float w0 = __expf(av.x) * i0;
        float w1 = __expf(av.y) * i1;
        float w2 = __expf(av.z) * i2;
        float w3 = __expf(av.w) * i3;
        const unsigned short* hr = h + (size_t)sn * 256;
        acc += b2f(hr[lane]) * w0 + b2f(hr[64 + lane]) * w1 +
               b2f(hr[128 + lane]) * w2 + b2f(hr[192 + lane]) * w3;
    }
    acc += bias[lane];
    float nr = acc * acc;
    #pragma unroll
    for (int s = 32; s; s >>= 1) nr += __shfl_xor(nr, s);
    float invn = 1.f / fmaxf(sqrtf(nr), 1e-8f);
    out[(size_t)n * 64 + lane] = acc * invn;
}

// ---------------------------------------------------------------------------
__global__ void lfocus_partial_k(const float* __restrict__ delta,
                                 float* __restrict__ part, int count) {
    __shared__ float sd[256];
    float s = 0.f;
    for (int i = blockIdx.x * 256 + threadIdx.x; i < count; i += gridDim.x * 256) {
        float v = delta[i];
        s += v * v;
    }
    sd[threadIdx.x] = s;
    __syncthreads();
    for (int st = 128; st; st >>= 1) {
        if (threadIdx.x < st) sd[threadIdx.x] += sd[threadIdx.x + st];
        __syncthreads();
    }
    if (threadIdx.x == 0) part[blockIdx.x] = sd[0];
}

__global__ void lfocus_final_k(const float* __restrict__ part, int nb,
                               float* __restrict__ outp) {
    __shared__ float sd[256];
    float s = 0.f;
    for (int i = threadIdx.x; i < nb; i += 256) s += part[i];
    sd[threadIdx.x] = s;
    __syncthreads();
    for (int st = 128; st; st >>= 1) {
        if (threadIdx.x < st) sd[threadIdx.x] += sd[threadIdx.x + st];
        __syncthreads();
    }
    if (threadIdx.x == 0) outp[0] = sd[0] / (float)((size_t)NN * KK);
}

// ---------------------------------------------------------------------------
extern "C" void kernel_launch(void* const* d_in, const int* in_sizes, int n_in,
                              void* d_out, int out_size, void* d_ws, size_t ws_size,
                              hipStream_t stream) {
    const float* h_l       = (const float*)d_in[0];
    const float* e_l       = (const float*)d_in[1];
    const int*   src       = (const int*)d_in[2];
    const int*   dst       = (const int*)d_in[3];
    const float* W_phi     = (const float*)d_in[4];
    const float* W1        = (const float*)d_in[5];
    const float* b1        = (const float*)d_in[6];
    const float* W2        = (const float*)d_in[7];
    const float* b2        = (const float*)d_in[8];
    const float* tilde_phi = (const float*)d_in[9];
    const float* W         = (const float*)d_in[10];
    const float* bias      = (const float*)d_in[11];
    float* out = (float*)d_out;

    char* ws = (char*)d_ws;
    size_t off = 0;
    auto alloc = [&](size_t bytes) -> char* {
        char* p = ws + off;
        off += (bytes + 255) & ~(size_t)255;
        return p;
    };
    float*          phi     = (float*)alloc((size_t)NN * 16 * 4);
    float*          delta   = (float*)alloc((size_t)NN * 64 * 4);
    unsigned short* h_bf    = (unsigned short*)alloc((size_t)NN * 256 * 2);
    unsigned short* hid_bf  = (unsigned short*)alloc((size_t)NN * 256 * 2);
    unsigned short* e_bf    = (unsigned short*)alloc((size_t)NN * 128 * 2);
    unsigned short* hl_bf   = (unsigned short*)alloc((size_t)NN * 256 * 2);
    float*          csr_a   = (float*)alloc((size_t)EE * 4 * 4);
    int*            csr_src = (int*)alloc((size_t)EE * 4);
    int*            deg     = (int*)alloc((size_t)NN * 4);
    int*            offs    = (int*)alloc((size_t)(NN + 1) * 4);
    int*            cursor  = (int*)alloc((size_t)NN * 4);
    int*            bsum    = (int*)alloc((size_t)SCAN_NB * 4);
    unsigned short* W_t     = (unsigned short*)alloc(256 * 256 * 2);
    unsigned short* W1_bf   = (unsigned short*)alloc(256 * 128 * 2);
    unsigned short* W2_bf   = (unsigned short*)alloc(64 * 256 * 2);
    unsigned short* Wphi_t  = (unsigned short*)alloc(16 * 128 * 2);
    float*          tnorm   = (float*)alloc(64 * 4);
    float*          part    = (float*)alloc(512 * 4);

    hipMemsetAsync(deg, 0, (size_t)NN * 4, stream);

    tnorm_lsep_k<<<1, 64, 0, stream>>>(tilde_phi, tnorm, out + (size_t)NN * OUTD);

    // casts
    cast_bf16_k<<<(NN * 128 / 4 + 255) / 256, 256, 0, stream>>>(e_l, e_bf, NN * 128 / 4);
    cast_bf16_k<<<(NN * 256 / 4 + 255) / 256, 256, 0, stream>>>(h_l, hl_bf, NN * 256 / 4);
    cast_bf16_k<<<(256 * 128 / 4 + 255) / 256, 256, 0, stream>>>(W1, W1_bf, 256 * 128 / 4);
    cast_bf16_k<<<(64 * 256 / 4 + 255) / 256, 256, 0, stream>>>(W2, W2_bf, 64 * 256 / 4);
    tcast_k<<<(256 * 256 + 255) / 256, 256, 0, stream>>>(W, W_t, 256, 256, 256);
    tcast_k<<<(128 * 16 + 255) / 256, 256, 0, stream>>>(W_phi, Wphi_t, 128, 15, 16);

    const int MB = (NN + 127) / 128;   // 391
    mgemm_k<128, 16, 1, 2, 1, false, false><<<dim3(MB, 1), 256, 0, stream>>>(
        e_bf, Wphi_t, nullptr, phi, NN, 16);
    mgemm_k<128, 128, 2, 4, 4, true, true><<<dim3(MB, 2), 256, 0, stream>>>(
        e_bf, W1_bf, b1, hid_bf, NN, 256);
    mgemm_k<256, 64, 1, 2, 4, false, false><<<dim3(MB, 1), 256, 0, stream>>>(
        hid_bf, W2_bf, b2, delta, NN, 64);
    mgemm_k<256, 128, 2, 4, 4, false, true><<<dim3(MB, 2), 256, 0, stream>>>(
        hl_bf, W_t, nullptr, h_bf, NN, 256);

    // CSR build
    degree_k<<<3125, 256, 0, stream>>>(dst, deg);
    scan_partial_k<<<SCAN_NB, 256, 0, stream>>>(deg, bsum);
    scan_bsum_k<<<1, 256, 0, stream>>>(bsum);
    scan_scatter_k<<<SCAN_NB, 256, 0, stream>>>(deg, bsum, offs, cursor);

    // edge logits + scatter into CSR
    edge_k<<<3125, 256, 0, stream>>>(phi, delta, tnorm, src, dst, cursor, csr_src,
                                     (float4*)csr_a);

    // per-dst softmax + aggregation + normalize
    aggregate_k<<<12500, 256, 0, stream>>>(offs, csr_src, (const float4*)csr_a, h_bf,
                                           bias, out);

    // l_focus
    lfocus_partial_k<<<512, 256, 0, stream>>>(delta, part, NN * 64);
    lfocus_final_k<<<1, 256, 0, stream>>>(part, 512, out + (size_t)NN * OUTD + 1);
}